// Round 9
// baseline (2637.457 us; speedup 1.0000x reference)
//
#include <hip/hip_runtime.h>
#include <math.h>

#define NBLK 64
#define NTHR 640   // 10 waves: 8 compute + wave8 (dA + XP/XE fires) + wave9 (ae + dB)
#define LSEQ 1024

typedef unsigned int u32;
typedef unsigned short u16;
typedef unsigned long long u64;

// ---------------- scalar helpers ----------------
__device__ __forceinline__ float bf2f(u16 u){ union{u32 i;float f;}v; v.i=(u32)u<<16; return v.f; }
__device__ __forceinline__ u16 f2bf(float f){ union{float f;u32 i;}v; v.f=f; u32 x=v.i;
  return (u16)((x + 0x7fffu + ((x>>16)&1u)) >> 16); }
__device__ __forceinline__ float u2f(u32 u){ union{u32 i;float f;}v; v.i=u; return v.f; }
__device__ __forceinline__ u32  f2u(float f){ union{float f;u32 i;}v; v.f=f; return v.i; }
__device__ __forceinline__ float sigm(float x){ return 1.f/(1.f+__expf(-x)); }

// coherent (agent-scope) 8B atoms: (tag<<32)|payload
__device__ __forceinline__ u64 gld64(const u64* p){ return __hip_atomic_load(const_cast<u64*>(p), __ATOMIC_RELAXED, __HIP_MEMORY_SCOPE_AGENT); }
__device__ __forceinline__ void gst64(u64* p, u64 v){ __hip_atomic_store(p, v, __ATOMIC_RELAXED, __HIP_MEMORY_SCOPE_AGENT); }
__device__ __forceinline__ u64 pollt(const u64* p, u32 tag){
  u64 v; int n = 0;
  do { v = gld64(p); } while ((u32)(v>>32) != tag && ++n < (1<<20));
  return v;
}
// LDS workgroup-scope flags
__device__ __forceinline__ u32 lldw(const u32* p){ return __hip_atomic_load(const_cast<u32*>(p), __ATOMIC_ACQUIRE, __HIP_MEMORY_SCOPE_WORKGROUP); }
__device__ __forceinline__ void lstw(u32* p, u32 v){ __hip_atomic_store(p, v, __ATOMIC_RELEASE, __HIP_MEMORY_SCOPE_WORKGROUP); }
__device__ __forceinline__ void lwait(const u32* p, int target){
  int n=0; while ((int)lldw(p) < target){ if(++n > (1<<20)) break; }
}

// ---------------- reductions ----------------
__device__ __forceinline__ float wred(float a){
  a += __int_as_float(__builtin_amdgcn_update_dpp(0, __float_as_int(a), 0x111, 0xf, 0xf, true));
  a += __int_as_float(__builtin_amdgcn_update_dpp(0, __float_as_int(a), 0x112, 0xf, 0xf, true));
  a += __int_as_float(__builtin_amdgcn_update_dpp(0, __float_as_int(a), 0x114, 0xf, 0xf, true));
  a += __int_as_float(__builtin_amdgcn_update_dpp(0, __float_as_int(a), 0x118, 0xf, 0xf, true));
  a += __int_as_float(__builtin_amdgcn_update_dpp(0, __float_as_int(a), 0x142, 0xa, 0xf, true));
  a += __int_as_float(__builtin_amdgcn_update_dpp(0, __float_as_int(a), 0x143, 0xc, 0xf, true));
  return __int_as_float(__builtin_amdgcn_readlane(__float_as_int(a), 63));
}
__device__ __forceinline__ float wredsh(float a){
  #pragma unroll
  for (int off = 32; off; off >>= 1) a += __shfl_xor(a, off);
  return a;
}
__device__ __forceinline__ float wredmaxsh(float a){
  #pragma unroll
  for (int off = 32; off; off >>= 1) a = fmaxf(a, __shfl_xor(a, off));
  return a;
}

// ---------------- packed dot helpers ----------------
__device__ __forceinline__ float dot8p(uint4 w, float4 a, float4 b2){
  float s;
  s  = u2f(w.x<<16)*a.x  + u2f(w.x&0xffff0000u)*a.y;
  s += u2f(w.y<<16)*a.z  + u2f(w.y&0xffff0000u)*a.w;
  s += u2f(w.z<<16)*b2.x + u2f(w.z&0xffff0000u)*b2.y;
  s += u2f(w.w<<16)*b2.z + u2f(w.w&0xffff0000u)*b2.w;
  return s;
}
__device__ __forceinline__ float dot4f(float4 w, float4 x){
  return w.x*x.x + w.y*x.y + w.z*x.z + w.w*x.w;
}
__device__ __forceinline__ uint4 pk8(float4 a, float4 b2){
  uint4 r;
  r.x = (u32)f2bf(a.x)  | ((u32)f2bf(a.y)<<16);
  r.y = (u32)f2bf(a.z)  | ((u32)f2bf(a.w)<<16);
  r.z = (u32)f2bf(b2.x) | ((u32)f2bf(b2.y)<<16);
  r.w = (u32)f2bf(b2.z) | ((u32)f2bf(b2.w)<<16);
  return r;
}
// select element i (0..7) of the 8 floats {a,b2}; i wave-uniform
__device__ __forceinline__ float sel8(float4 a, float4 b2, int i){
  float lo = (i&2) ? ((i&1)? a.w : a.z) : ((i&1)? a.y : a.x);
  float hi = (i&2) ? ((i&1)? b2.w : b2.z) : ((i&1)? b2.y : b2.x);
  return (i&4) ? hi : lo;
}

#define SMEM_BYTES 142208

// pipeline shift (end of every phase): dA reads at d2 (lag 2), dB at d3 (lag 3),
// ae at e2 (lag 2). Margins (w8d>=ph-1, w9d>=ph-2): XP 4-slot, XS 4-slot, XE 8-slot.
#define SHIFT() do { \
  d3V=d2V; d3Slot=d2Slot; d3o1=d2o1; d3Tag=d2Tag; d3cur=d2cur; d3arg=d2arg; \
  d2V=d1V; d2Slot=d1Slot; d2o1=d1o1; d2o2=d1o2; d2Tag=d1Tag; d2cur=d1cur; d2arg=d1arg; \
  d1V=0; \
  e2V=e1V; e2Slot=e1Slot; e2Own=e1Own; e2Tag=e1Tag; e2Sel=e1Sel; \
  e1V=0; \
} while(0)

// wave8: dA — batched 32-column poll of XP (tag fired 2 phases ago), publish to XS.
// Runs BEFORE lwait so its latency hides under the compute waves' phase.
#define W8_DA() do { \
  if (d2V && (b == d2o1 || b == d2o2)){ \
    int half_ = (b == d2o2) ? 1 : 0; \
    const u64* P_ = XP + ((size_t)(d2Slot*64 + lane))*64 + half_*32; \
    u64 vv_[32]; int bad_; int nn_ = 0; \
    do { bad_ = 0; \
      _Pragma("unroll") for (int j_ = 0; j_ < 32; ++j_) vv_[j_] = gld64(P_ + j_); \
      _Pragma("unroll") for (int j_ = 0; j_ < 32; ++j_) bad_ |= (int)((u32)(vv_[j_]>>32) != d2Tag); \
    } while (bad_ && ++nn_ < (1<<20)); \
    float h0_ = 0.f, h1_ = 0.f; \
    _Pragma("unroll") for (int j_ = 0; j_ < 32; ++j_){ \
      h0_ += bf2f((u16)(vv_[j_] & 0xffff)); h1_ += bf2f((u16)((vv_[j_]>>16) & 0xffff)); } \
    gst64(&XS[half_*256 + d2Slot*64 + lane], ((u64)d2Tag<<32) | (u32)f2bf(h0_) | ((u32)f2bf(h1_)<<16)); \
  } \
} while(0)

// wave9: ae (edge 2-way log-softmax, lag 2) + dB (final dest log-softmax, lag 3)
#define W9_JOBS() do { \
  if (e2V && b == e2Own){ \
    u64 v_ = pollt(XE + e2Slot*64 + lane, e2Tag); \
    float p0_ = wredsh(bf2f((u16)(v_ & 0xffff))); \
    float p1_ = wredsh(bf2f((u16)((v_>>16) & 0xffff))); \
    if (lane == 0){ \
      float l0_ = p0_ + be2_0, l1_ = p1_ + be2_1; \
      float m_ = fmaxf(l0_, l1_); \
      nllw += m_ + logf(__expf(l0_-m_) + __expf(l1_-m_)) - (e2Sel ? l1_ : l0_); \
    } \
  } \
  if (d3V && b == d3o1){ \
    const u64* pa_ = &XS[d3Slot*64 + lane]; \
    const u64* pb_ = &XS[256 + d3Slot*64 + lane]; \
    u64 va_, vb_; int nn_ = 0; \
    do { va_ = gld64(pa_); vb_ = gld64(pb_); } \
    while ((((u32)(va_>>32) != d3Tag) || ((u32)(vb_>>32) != d3Tag)) && ++nn_ < (1<<20)); \
    float x0 = bf2f((u16)(va_ & 0xffff)) + bf2f((u16)(vb_ & 0xffff)); \
    float x1 = bf2f((u16)((va_>>16) & 0xffff)) + bf2f((u16)((vb_>>16) & 0xffff)); \
    x0 = (lane < d3cur)      ? x0 : -__builtin_inff(); \
    x1 = (lane + 64 < d3cur) ? x1 : -__builtin_inff(); \
    float m_ = wredmaxsh(fmaxf(x0, x1)); \
    float s_ = wredsh(__expf(x0 - m_) + __expf(x1 - m_)); \
    float la_ = (d3arg < 64) ? __shfl(x0, d3arg) : __shfl(x1, d3arg - 64); \
    if (lane == 0) nllw += (m_ + logf(s_)) - la_; \
  } \
} while(0)

__global__ void __launch_bounds__(NTHR, 1)
dgmg_kernel(const int* __restrict__ actions, const int* __restrict__ argseq,
            const float* __restrict__ node_init, const float* __restrict__ w_nip, const float* __restrict__ b_nip,
            const float* __restrict__ w_e1, const float* __restrict__ b_e1,
            const float* __restrict__ w_e2, const float* __restrict__ b_e2,
            const float* __restrict__ w_q, const float* __restrict__ b_q,
            const float* __restrict__ w_k,
            const float* __restrict__ wih_n, const float* __restrict__ whh_n,
            const float* __restrict__ bih_n, const float* __restrict__ bhh_n,
            const float* __restrict__ wih_g, const float* __restrict__ whh_g,
            const float* __restrict__ bih_g, const float* __restrict__ bhh_g,
            const float* __restrict__ graph0,
            float* __restrict__ out, unsigned char* __restrict__ ws)
{
  extern __shared__ unsigned char smem[];
  u16* s_wihg = (u16*)smem;                 // [24][512] packed bf16
  u16* s_whhg = s_wihg + 24*512;
  u16* s_wihn = s_whhg + 24*512;
  u16* s_whhn = s_wihn + 24*512;
  u16* s_we1  = s_whhn + 24*512;            // [8][1024]
  u16* s_wq   = s_we1 + 8*1024;             // [8][1024]
  float* s_kloc = (float*)(s_wq + 8*1024);  // [8][128] k-cache [dim][node]
  u16*   s_gin  = (u16*)(s_kloc + 1024);    // [128][24] gi_n freeze cache
  float* s_bihg = (float*)(s_gin + 128*24); // [24]
  float* s_bhhg = s_bihg + 24;
  float* s_bihn = s_bhhg + 24;
  float* s_bhhn = s_bihn + 24;
  float* s_be1  = s_bhhn + 24;              // [8]
  float* s_bq   = s_be1 + 8;                // [8]
  float* s_q8   = s_bq + 8;                 // [4][8]  (slot = ph&3)
  float* s_red  = s_q8 + 32;                // [4][16] (slot = ph&3)
  u32*   s_wfl  = (u32*)(s_red + 64);       // [8] per-wave phase flags
  u32*   s_w8d  = s_wfl + 8;                // wave8 done
  u32*   s_w9d  = s_w8d + 1;                // wave9 done

  const int b = blockIdx.x, tid = threadIdx.x;
  const int wv = tid >> 6, lane = tid & 63;
  const int d = b*8 + ((wv < 8) ? wv : 0);

  // workspace: tagged u64 atoms
  u64* Xng = (u64*)ws;         // [4][512][2]: per dim {ncur, g} adjacent, slot=tag&3
  u64* Xh  = Xng + 4096;       // [512] h0 broadcast (tag 1)
  u64* XE  = Xh + 512;         // [8][64] edge-logit partials
  u64* XP  = XE + 512;         // [4][64][64] dest-logit partials
  u64* XS  = XP + 16384;       // [2][4][64] dest half-sums
  u64* XN  = XS + 512;         // [64] final nll pieces

  // ---------------- init: biases + packed bf16 weight slices ----------------
  if (tid < 24){
    int ld = tid/3, gt = tid%3;
    int row = gt*512 + b*8 + ld;
    s_bihg[tid] = bih_g[row]; s_bhhg[tid] = bhh_g[row];
    s_bihn[tid] = bih_n[row]; s_bhhn[tid] = bhh_n[row];
  }
  if (tid < 8){ s_be1[tid] = b_e1[b*8+tid]; s_bq[tid] = b_q[b*8+tid]; }
  if (tid == 0){
    #pragma unroll
    for (int w = 0; w < 8; ++w) s_wfl[w] = 1u;
    s_w8d[0] = 1u; s_w9d[0] = 1u;
  }

  for (int r = wv; r < 24; r += 10){
    int ld = r/3, gt = r%3;
    long grow = (long)(gt*512 + b*8 + ld) * 512;
    float4 a0, a1;
    a0 = *(const float4*)&wih_g[grow + lane*8]; a1 = *(const float4*)&wih_g[grow + lane*8 + 4];
    *(uint4*)&s_wihg[r*512 + lane*8] = pk8(a0, a1);
    a0 = *(const float4*)&whh_g[grow + lane*8]; a1 = *(const float4*)&whh_g[grow + lane*8 + 4];
    *(uint4*)&s_whhg[r*512 + lane*8] = pk8(a0, a1);
    a0 = *(const float4*)&wih_n[grow + lane*8]; a1 = *(const float4*)&wih_n[grow + lane*8 + 4];
    *(uint4*)&s_wihn[r*512 + lane*8] = pk8(a0, a1);
    a0 = *(const float4*)&whh_n[grow + lane*8]; a1 = *(const float4*)&whh_n[grow + lane*8 + 4];
    *(uint4*)&s_whhn[r*512 + lane*8] = pk8(a0, a1);
  }
  if (wv < 8){
    long grow = (long)(b*8 + wv) * 1024;
    #pragma unroll
    for (int h = 0; h < 2; ++h){
      float4 a0 = *(const float4*)&w_e1[grow + h*512 + lane*8];
      float4 a1 = *(const float4*)&w_e1[grow + h*512 + lane*8 + 4];
      *(uint4*)&s_we1[wv*1024 + h*512 + lane*8] = pk8(a0, a1);
      float4 q0 = *(const float4*)&w_q[grow + h*512 + lane*8];
      float4 q1 = *(const float4*)&w_q[grow + h*512 + lane*8 + 4];
      *(uint4*)&s_wq[wv*1024 + h*512 + lane*8] = pk8(q0, q1);
    }
  }
  __syncthreads();   // weights + biases staged (only barrier in the kernel)

  float we2_0 = w_e2[d], we2_1 = w_e2[512+d];
  float be2_0 = b_e2[0], be2_1 = b_e2[1];
  float nllw = 0.f;

  float cbg_r=0,cbg_z=0,bg_ni=0,bg_nh=0, bh_gr=0,bh_gz=0;
  float bn_r=0,bn_z=0,bn_nh=0, fb_r=0,fb_z=0,fb_n=0, be1w=0,bqw=0;
  if (wv < 8){
    cbg_r = s_bihg[wv*3+0]+s_bhhg[wv*3+0];
    cbg_z = s_bihg[wv*3+1]+s_bhhg[wv*3+1];
    bg_ni = s_bihg[wv*3+2]; bg_nh = s_bhhg[wv*3+2];
    bh_gr = s_bhhg[wv*3+0]; bh_gz = s_bhhg[wv*3+1];
    bn_r = s_bhhn[wv*3+0]; bn_z = s_bhhn[wv*3+1]; bn_nh = s_bhhn[wv*3+2];
    fb_r = s_bihn[wv*3+0]; fb_z = s_bihn[wv*3+1]; fb_n = s_bihn[wv*3+2];
    be1w = s_be1[wv]; bqw = s_bq[wv];
    // h0 fire (tag 1): each lane reads node_init directly
    float4 xa = *(const float4*)&node_init[lane*8];
    float4 xb = *(const float4*)&node_init[lane*8+4];
    const float* wr = w_nip + (long)d*512;
    float4 wa = *(const float4*)&wr[lane*8], wb2 = *(const float4*)&wr[lane*8+4];
    float h0d = wred(dot4f(wa,xa)+dot4f(wb2,xb)) + b_nip[d];
    if (lane == 0) gst64(&Xh[d], (1ull<<32) | f2u(h0d));
  }
  u32 ph = 2;

  // per-wave persistent register state
  float4 h0_a = make_float4(0,0,0,0), h0_b = make_float4(0,0,0,0);
  float4 xc_a = make_float4(0,0,0,0), xc_b = make_float4(0,0,0,0);
  float gi0r=0,gi0z=0,gi0n=0, ghn0r=0,ghn0z=0,ghn0n=0;

  // job pipeline state (uniform trace walk)
  int d1V=0,d1Slot=0,d1o1=0,d1o2=0,d1cur=0,d1arg=0; u32 d1Tag=0;
  int d2V=0,d2Slot=0,d2o1=0,d2o2=0,d2cur=0,d2arg=0; u32 d2Tag=0;
  int d3V=0,d3Slot=0,d3o1=0,d3cur=0,d3arg=0; u32 d3Tag=0;
  int e1V=0,e1Slot=0,e1Own=0,e1Sel=0; u32 e1Tag=0;
  int e2V=0,e2Slot=0,e2Own=0,e2Sel=0; u32 e2Tag=0;
  int ecnt=0, dcnt=0;

  int cur = -1, have_se = 0;
  bool first_an = true;

  // ---------------- main sequential scan (NO barriers) ----------------
  for (int t = 0; t < LSEQ; ++t){
    int a = actions[t];
    if (a == 1) continue;
    if (a == 3){ have_se = 1; continue; }
    if (a < 0 || a >= 4) continue;

    int t1 = (t+1 < LSEQ) ? actions[t+1] : -1;
    int nxt = (t1 == 1);
    int i2 = (t+2 < LSEQ) ? t+2 : LSEQ-1;
    int chn = nxt ? argseq[i2] : 0;

    u32 tg = ph-1; int ps = (int)(tg&3), pf = (int)(ph&3);
    // throttle: tight slacks so all slot-reuse margins are provable
    { int n=0; while ((int)lldw(s_w8d) < (int)ph-1){ if(++n>(1<<20)) break; } }
    { int n=0; while ((int)lldw(s_w9d) < (int)ph-2){ if(++n>(1<<20)) break; } }

    if (a == 0){ // ======== ADD_NODE ========
      int se = have_se;
      int eslot = ecnt & 7;
      if (wv < 8){
        const u32* Win = (const u32*)s_wihn;
        float fr=0.f, fz=0.f, fn=0.f;
        if (cur >= 0){ // freeze prev node (no polled deps) — overlaps g in flight
          fr = wred(dot8p(*(const uint4*)&Win[(wv*3+0)*256+lane*4], xc_a,xc_b)) + fb_r;
          fz = wred(dot8p(*(const uint4*)&Win[(wv*3+1)*256+lane*4], xc_a,xc_b)) + fb_z;
          fn = wred(dot8p(*(const uint4*)&Win[(wv*3+2)*256+lane*4], xc_a,xc_b)) + fb_n;
          const float* wkr = w_k + (long)d*512;
          float4 ka = *(const float4*)&wkr[lane*8], kb2 = *(const float4*)&wkr[lane*8+4];
          float kv = wred(dot4f(ka,xc_a)+dot4f(kb2,xc_b));
          if (lane == 0){
            s_gin[cur*24+wv*3+0] = f2bf(fr); s_gin[cur*24+wv*3+1] = f2bf(fz); s_gin[cur*24+wv*3+2] = f2bf(fn);
            s_kloc[wv*128 + cur] = kv;
          }
        }
        if (nxt){ // early ncur fire: ncur1 = GRU_n(chosen1, h0) — all from caches
          float gr = (chn == cur && cur >= 0) ? fr : bf2f(s_gin[chn*24+wv*3+0]);
          float gz = (chn == cur && cur >= 0) ? fz : bf2f(s_gin[chn*24+wv*3+1]);
          float gn = (chn == cur && cur >= 0) ? fn : bf2f(s_gin[chn*24+wv*3+2]);
          float r2 = sigm(gr + ghn0r), z2 = sigm(gz + ghn0z);
          float n2 = tanhf(gn + r2*ghn0n);
          float h0d = __shfl(sel8(h0_a, h0_b, wv), b);
          if (lane == 0) gst64(&Xng[((size_t)pf*512+d)*2], ((u64)ph<<32) | f2u((1.f-z2)*n2 + z2*h0d));
        }
        // poll g (register-direct; lane l holds dims 8l..8l+7)
        float4 xg_a, xg_b;
        if (first_an){
          u64 v[8]; int nn=0;
          const u64* P = Xh + lane*8;
          for (;;){
            #pragma unroll
            for (int k = 0; k < 8; ++k) v[k] = gld64(P + k);
            int ok = 1;
            #pragma unroll
            for (int k = 0; k < 8; ++k) ok &= (int)((u32)(v[k]>>32) == 1u);
            if (__all(ok)) break;
            if (++nn > (1<<20)) break;
          }
          h0_a = make_float4(u2f((u32)v[0]),u2f((u32)v[1]),u2f((u32)v[2]),u2f((u32)v[3]));
          h0_b = make_float4(u2f((u32)v[4]),u2f((u32)v[5]),u2f((u32)v[6]),u2f((u32)v[7]));
          xg_a = *(const float4*)&graph0[lane*8];
          xg_b = *(const float4*)&graph0[lane*8+4];
          const u32* Wig = (const u32*)s_wihg; const u32* Wn = (const u32*)s_whhn;
          gi0r = wred(dot8p(*(const uint4*)&Wig[(wv*3+0)*256+lane*4], h0_a,h0_b)) + s_bihg[wv*3+0];
          gi0z = wred(dot8p(*(const uint4*)&Wig[(wv*3+1)*256+lane*4], h0_a,h0_b)) + s_bihg[wv*3+1];
          gi0n = wred(dot8p(*(const uint4*)&Wig[(wv*3+2)*256+lane*4], h0_a,h0_b)) + s_bihg[wv*3+2];
          ghn0r = wred(dot8p(*(const uint4*)&Wn[(wv*3+0)*256+lane*4], h0_a,h0_b)) + bn_r;
          ghn0z = wred(dot8p(*(const uint4*)&Wn[(wv*3+1)*256+lane*4], h0_a,h0_b)) + bn_z;
          ghn0n = wred(dot8p(*(const uint4*)&Wn[(wv*3+2)*256+lane*4], h0_a,h0_b)) + bn_nh;
        } else {
          u64 v[8]; int nn=0;
          const u64* P = Xng + ((size_t)ps*512 + lane*8)*2 + 1;
          for (;;){
            #pragma unroll
            for (int k = 0; k < 8; ++k) v[k] = gld64(P + 2*k);
            int ok = 1;
            #pragma unroll
            for (int k = 0; k < 8; ++k) ok &= (int)((u32)(v[k]>>32) == tg);
            if (__all(ok)) break;
            if (++nn > (1<<20)) break;
          }
          xg_a = make_float4(u2f((u32)v[0]),u2f((u32)v[1]),u2f((u32)v[2]),u2f((u32)v[3]));
          xg_b = make_float4(u2f((u32)v[4]),u2f((u32)v[5]),u2f((u32)v[6]),u2f((u32)v[7]));
        }
        { // g' = GRU_g(h0, g): fire ASAP
          const u32* Whg = (const u32*)s_whhg;
          float ghr = wred(dot8p(*(const uint4*)&Whg[(wv*3+0)*256+lane*4], xg_a,xg_b)) + bh_gr;
          float ghz = wred(dot8p(*(const uint4*)&Whg[(wv*3+1)*256+lane*4], xg_a,xg_b)) + bh_gz;
          float ghn = wred(dot8p(*(const uint4*)&Whg[(wv*3+2)*256+lane*4], xg_a,xg_b)) + bg_nh;
          float r_ = sigm(gi0r + ghr), z_ = sigm(gi0z + ghz);
          float n_ = tanhf(gi0n + r_*ghn);
          float gd = __shfl(sel8(xg_a, xg_b, wv), b);
          if (lane == 0) gst64(&Xng[((size_t)pf*512+d)*2+1], ((u64)ph<<32) | f2u((1.f-z_)*n_ + z_*gd));
        }
        if (se){ // deferred STOP_EDGE e-partials (uses OLD xc)
          const u32* Re = (const u32*)s_we1 + wv*512;
          float pe = dot8p(*(const uint4*)&Re[lane*4], xg_a,xg_b) + dot8p(*(const uint4*)&Re[256+lane*4], xc_a,xc_b);
          float hv = fmaxf(wred(pe) + be1w, 0.f);
          if (lane == 0){ s_red[pf*16 + wv*2] = hv*we2_0; s_red[pf*16 + wv*2+1] = hv*we2_1; }
        }
        xc_a = h0_a; xc_b = h0_b;             // new current node
        if (lane == 0) lstw(&s_wfl[wv], ph);
      }
      if (wv == 8){
        W8_DA();                               // before lwait: hidden under compute
        #pragma unroll 1
        for (int w = 0; w < 8; ++w) lwait(&s_wfl[w], (int)ph);
        if (se && lane == 0){
          float p0 = 0.f, p1 = 0.f;
          #pragma unroll
          for (int i = 0; i < 8; ++i){ p0 += s_red[pf*16 + i*2]; p1 += s_red[pf*16 + i*2+1]; }
          gst64(&XE[eslot*64 + b], ((u64)ph<<32) | (u32)f2bf(p0) | ((u32)f2bf(p1)<<16));
        }
        if (lane == 0) lstw(s_w8d, ph);
      }
      if (wv == 9){
        W9_JOBS();
        if (lane == 0) lstw(s_w9d, ph);
      }
      SHIFT();
      if (se){ e1V=1; e1Slot=eslot; e1Sel=1; e1Own=ecnt&63; e1Tag=ph; ecnt++; }
      have_se = 0; first_an = false;
      cur += 1; ph += 1;
    }
    else { // ======== CHOOSE_DEST ========
      int arg = argseq[t];
      int eslot = ecnt & 7, dslot = dcnt & 3;
      if (wv < 8){
        // poll {ncur, g} — 16 contiguous atoms per lane
        u64 v[16]; int nn=0;
        const u64* P = Xng + ((size_t)ps*512 + lane*8)*2;
        for (;;){
          #pragma unroll
          for (int k = 0; k < 16; ++k) v[k] = gld64(P + k);
          int ok = 1;
          #pragma unroll
          for (int k = 0; k < 16; ++k) ok &= (int)((u32)(v[k]>>32) == tg);
          if (__all(ok)) break;
          if (++nn > (1<<20)) break;
        }
        float4 xn_a = make_float4(u2f((u32)v[0]), u2f((u32)v[2]), u2f((u32)v[4]), u2f((u32)v[6]));
        float4 xn_b = make_float4(u2f((u32)v[8]), u2f((u32)v[10]),u2f((u32)v[12]),u2f((u32)v[14]));
        float4 xg_a = make_float4(u2f((u32)v[1]), u2f((u32)v[3]), u2f((u32)v[5]), u2f((u32)v[7]));
        float4 xg_b = make_float4(u2f((u32)v[9]), u2f((u32)v[11]),u2f((u32)v[13]),u2f((u32)v[15]));
        const u32* Wn = (const u32*)s_whhn; const u32* Wig = (const u32*)s_wihg; const u32* Whg = (const u32*)s_whhg;
        { // 1) fire g_j FIRST (critical chain)
          float pr = dot8p(*(const uint4*)&Wig[(wv*3+0)*256+lane*4], xn_a,xn_b)
                   + dot8p(*(const uint4*)&Whg[(wv*3+0)*256+lane*4], xg_a,xg_b);
          float pz = dot8p(*(const uint4*)&Wig[(wv*3+1)*256+lane*4], xn_a,xn_b)
                   + dot8p(*(const uint4*)&Whg[(wv*3+1)*256+lane*4], xg_a,xg_b);
          float r_ = sigm(wred(pr) + cbg_r);
          float z_ = sigm(wred(pz) + cbg_z);
          float gin_ = wred(dot8p(*(const uint4*)&Wig[(wv*3+2)*256+lane*4], xn_a,xn_b)) + bg_ni;
          float ghn_ = wred(dot8p(*(const uint4*)&Whg[(wv*3+2)*256+lane*4], xg_a,xg_b)) + bg_nh;
          float n_ = tanhf(gin_ + r_*ghn_);
          float gd = __shfl(sel8(xg_a, xg_b, wv), b);
          if (lane == 0) gst64(&Xng[((size_t)pf*512+d)*2+1], ((u64)ph<<32) | f2u((1.f-z_)*n_ + z_*gd));
        }
        if (nxt){ // 2) fire ncur_{j+1} = GRU_n(chosen_{j+1}, ncur_j)
          float ghr = wred(dot8p(*(const uint4*)&Wn[(wv*3+0)*256+lane*4], xn_a,xn_b)) + bn_r;
          float ghz = wred(dot8p(*(const uint4*)&Wn[(wv*3+1)*256+lane*4], xn_a,xn_b)) + bn_z;
          float ghn = wred(dot8p(*(const uint4*)&Wn[(wv*3+2)*256+lane*4], xn_a,xn_b)) + bn_nh;
          float gr = bf2f(s_gin[chn*24+wv*3+0]), gz = bf2f(s_gin[chn*24+wv*3+1]), gn = bf2f(s_gin[chn*24+wv*3+2]);
          float r_ = sigm(gr+ghr), z_ = sigm(gz+ghz);
          float n_ = tanhf(gn + r_*ghn);
          float ncd = __shfl(sel8(xn_a, xn_b, wv), b);
          if (lane == 0) gst64(&Xng[((size_t)pf*512+d)*2], ((u64)ph<<32) | f2u((1.f-z_)*n_ + z_*ncd));
        }
        { // 3) q_j + AE e-partials from (g_{j-1}, curv_{j-1})
          const u32* Rq = (const u32*)s_wq + wv*512;
          float pq = dot8p(*(const uint4*)&Rq[lane*4], xg_a,xg_b) + dot8p(*(const uint4*)&Rq[256+lane*4], xc_a,xc_b);
          float qd = wred(pq) + bqw;
          const u32* Re = (const u32*)s_we1 + wv*512;
          float pe = dot8p(*(const uint4*)&Re[lane*4], xg_a,xg_b) + dot8p(*(const uint4*)&Re[256+lane*4], xc_a,xc_b);
          float hv = fmaxf(wred(pe) + be1w, 0.f);
          if (lane == 0){ s_q8[pf*8+wv] = qd; s_red[pf*16+wv*2] = hv*we2_0; s_red[pf*16+wv*2+1] = hv*we2_1; }
        }
        xc_a = xn_a; xc_b = xn_b;             // curv becomes ncur_j
        if (lane == 0) lstw(&s_wfl[wv], ph);
      }
      if (wv == 8){
        W8_DA();                               // before lwait: hidden under compute
        #pragma unroll 1
        for (int w = 0; w < 8; ++w) lwait(&s_wfl[w], (int)ph);
        { // XP fire: dest-logit partials (local k x local q)
          float pl0 = 0.f, pl1 = 0.f;
          #pragma unroll
          for (int k = 0; k < 8; ++k){
            float qk = s_q8[pf*8 + k];
            pl0 += s_kloc[k*128 + lane]      * qk;
            pl1 += s_kloc[k*128 + lane + 64] * qk;
          }
          gst64(&XP[((size_t)(dslot*64 + lane))*64 + b], ((u64)ph<<32) | (u32)f2bf(pl0) | ((u32)f2bf(pl1)<<16));
        }
        if (lane == 0){ // XE fire
          float p0 = 0.f, p1 = 0.f;
          #pragma unroll
          for (int i = 0; i < 8; ++i){ p0 += s_red[pf*16 + i*2]; p1 += s_red[pf*16 + i*2+1]; }
          gst64(&XE[eslot*64 + b], ((u64)ph<<32) | (u32)f2bf(p0) | ((u32)f2bf(p1)<<16));
        }
        if (lane == 0) lstw(s_w8d, ph);
      }
      if (wv == 9){
        W9_JOBS();
        if (lane == 0) lstw(s_w9d, ph);
      }
      SHIFT();
      e1V=1; e1Slot=eslot; e1Sel=0; e1Own=ecnt&63; e1Tag=ph; ecnt++;
      d1V=1; d1Slot=dslot; d1o1=(2*dcnt)&63; d1o2=(2*dcnt+1)&63; d1cur=cur; d1arg=arg; d1Tag=ph; dcnt++;
      ph += 1;
    }
  }

  // ---------------- drain: SE phase + 4 flush phases ----------------
  {
    int se = have_se;
    int eslot = ecnt & 7;
    u32 tg = ph-1; int ps = (int)(tg&3), pf = (int)(ph&3);
    { int n=0; while ((int)lldw(s_w8d) < (int)ph-1){ if(++n>(1<<20)) break; } }
    { int n=0; while ((int)lldw(s_w9d) < (int)ph-2){ if(++n>(1<<20)) break; } }
    if (wv < 8){
      u64 v[8]; int nn=0;
      const u64* P = Xng + ((size_t)ps*512 + lane*8)*2 + 1;
      for (;;){
        #pragma unroll
        for (int k = 0; k < 8; ++k) v[k] = gld64(P + 2*k);
        int ok = 1;
        #pragma unroll
        for (int k = 0; k < 8; ++k) ok &= (int)((u32)(v[k]>>32) == tg);
        if (__all(ok)) break;
        if (++nn > (1<<20)) break;
      }
      if (se){
        float4 xg_a = make_float4(u2f((u32)v[0]),u2f((u32)v[1]),u2f((u32)v[2]),u2f((u32)v[3]));
        float4 xg_b = make_float4(u2f((u32)v[4]),u2f((u32)v[5]),u2f((u32)v[6]),u2f((u32)v[7]));
        const u32* Re = (const u32*)s_we1 + wv*512;
        float pe = dot8p(*(const uint4*)&Re[lane*4], xg_a,xg_b) + dot8p(*(const uint4*)&Re[256+lane*4], xc_a,xc_b);
        float hv = fmaxf(wred(pe) + be1w, 0.f);
        if (lane == 0){ s_red[pf*16+wv*2] = hv*we2_0; s_red[pf*16+wv*2+1] = hv*we2_1; }
      }
      if (lane == 0) lstw(&s_wfl[wv], ph);
    }
    if (wv == 8){
      W8_DA();
      #pragma unroll 1
      for (int w = 0; w < 8; ++w) lwait(&s_wfl[w], (int)ph);
      if (se && lane == 0){
        float p0 = 0.f, p1 = 0.f;
        #pragma unroll
        for (int i = 0; i < 8; ++i){ p0 += s_red[pf*16 + i*2]; p1 += s_red[pf*16 + i*2+1]; }
        gst64(&XE[eslot*64 + b], ((u64)ph<<32) | (u32)f2bf(p0) | ((u32)f2bf(p1)<<16));
      }
      if (lane == 0) lstw(s_w8d, ph);
    }
    if (wv == 9){
      W9_JOBS();
      if (lane == 0) lstw(s_w9d, ph);
    }
    SHIFT();
    if (se){ e1V=1; e1Slot=eslot; e1Sel=1; e1Own=ecnt&63; e1Tag=ph; ecnt++; }
    ph += 1;
  }
  #pragma unroll 1
  for (int dp = 0; dp < 4; ++dp){
    { int n=0; while ((int)lldw(s_w8d) < (int)ph-1){ if(++n>(1<<20)) break; } }
    { int n=0; while ((int)lldw(s_w9d) < (int)ph-2){ if(++n>(1<<20)) break; } }
    if (wv < 8){
      if (lane == 0) lstw(&s_wfl[wv], ph);
    }
    if (wv == 8){
      W8_DA();
      #pragma unroll 1
      for (int w = 0; w < 8; ++w) lwait(&s_wfl[w], (int)ph);
      if (lane == 0) lstw(s_w8d, ph);
    }
    if (wv == 9){
      W9_JOBS();
      if (lane == 0) lstw(s_w9d, ph);
    }
    SHIFT();
    ph += 1;
  }
  // ---------------- final collect (all nll lives on wave 9) ----------------
  if (wv == 9){
    if (lane == 0) gst64(&XN[b], (0xFFFFull<<32) | f2u(nllw));
    if (b == 0){
      u64 v = pollt(&XN[lane], 0xFFFFu);
      float tot = wredsh(u2f((u32)v));
      if (lane == 0) out[0] = tot;
    }
  }
}

extern "C" void kernel_launch(void* const* d_in, const int* in_sizes, int n_in,
                              void* d_out, int out_size, void* d_ws, size_t ws_size,
                              hipStream_t stream) {
  (void)in_sizes; (void)n_in; (void)out_size; (void)ws_size;
  // zero all tag-atom regions (22080 u64) — exact-match tags then poison/replay-safe
  hipMemsetAsync(d_ws, 0, 176640, stream);
  hipFuncSetAttribute((const void*)dgmg_kernel,
                      hipFuncAttributeMaxDynamicSharedMemorySize, SMEM_BYTES);
  dgmg_kernel<<<NBLK, NTHR, SMEM_BYTES, stream>>>(
      (const int*)d_in[0], (const int*)d_in[1],
      (const float*)d_in[2], (const float*)d_in[3], (const float*)d_in[4],
      (const float*)d_in[5], (const float*)d_in[6],
      (const float*)d_in[7], (const float*)d_in[8],
      (const float*)d_in[9], (const float*)d_in[10],
      (const float*)d_in[11],                      /* w_k ; b_k unused (cancels) */
      (const float*)d_in[13], (const float*)d_in[14],
      (const float*)d_in[15], (const float*)d_in[16],
      (const float*)d_in[17], (const float*)d_in[18],
      (const float*)d_in[19], (const float*)d_in[20],
      (const float*)d_in[21],
      (float*)d_out, (unsigned char*)d_ws);
}

// Round 11
// 1103.354 us; speedup vs baseline: 2.3904x; 2.3904x over previous
//
#include <hip/hip_runtime.h>
#include <math.h>

#define NBLK 64
#define NTHR 576        // 9 waves: 8 compute + 1 fire/job wave
#define LSEQ 1024

typedef unsigned int u32;
typedef unsigned short u16;
typedef unsigned long long u64;

// ---------------- scalar helpers ----------------
__device__ __forceinline__ float bf2f(u16 u){ union{u32 i;float f;}v; v.i=(u32)u<<16; return v.f; }
__device__ __forceinline__ u16 f2bf(float f){ union{float f;u32 i;}v; v.f=f; u32 x=v.i;
  return (u16)((x + 0x7fffu + ((x>>16)&1u)) >> 16); }
__device__ __forceinline__ float u2f(u32 u){ union{u32 i;float f;}v; v.i=u; return v.f; }
__device__ __forceinline__ u32  f2u(float f){ union{float f;u32 i;}v; v.f=f; return v.i; }
__device__ __forceinline__ float sigm(float x){ return 1.f/(1.f+__expf(-x)); }

// coherent (agent-scope) 8B atoms: (tag<<32)|payload
__device__ __forceinline__ u64 gld64(const u64* p){ return __hip_atomic_load(const_cast<u64*>(p), __ATOMIC_RELAXED, __HIP_MEMORY_SCOPE_AGENT); }
__device__ __forceinline__ void gst64(u64* p, u64 v){ __hip_atomic_store(p, v, __ATOMIC_RELAXED, __HIP_MEMORY_SCOPE_AGENT); }
__device__ __forceinline__ u64 pollt(const u64* p, u32 tag){
  u64 v; int n = 0;
  do { v = gld64(p); } while ((u32)(v>>32) != tag && ++n < (1<<20));
  return v;
}

// ---------------- reductions ----------------
// DPP full-wave(64) sum; result uniform. VALU-only.
__device__ __forceinline__ float wred(float a){
  a += __int_as_float(__builtin_amdgcn_update_dpp(0, __float_as_int(a), 0x111, 0xf, 0xf, true));
  a += __int_as_float(__builtin_amdgcn_update_dpp(0, __float_as_int(a), 0x112, 0xf, 0xf, true));
  a += __int_as_float(__builtin_amdgcn_update_dpp(0, __float_as_int(a), 0x114, 0xf, 0xf, true));
  a += __int_as_float(__builtin_amdgcn_update_dpp(0, __float_as_int(a), 0x118, 0xf, 0xf, true));
  a += __int_as_float(__builtin_amdgcn_update_dpp(0, __float_as_int(a), 0x142, 0xa, 0xf, true));
  a += __int_as_float(__builtin_amdgcn_update_dpp(0, __float_as_int(a), 0x143, 0xc, 0xf, true));
  return __int_as_float(__builtin_amdgcn_readlane(__float_as_int(a), 63));
}
__device__ __forceinline__ float wredsh(float a){
  #pragma unroll
  for (int off = 32; off; off >>= 1) a += __shfl_xor(a, off);
  return a;
}
__device__ __forceinline__ float wredmaxsh(float a){
  #pragma unroll
  for (int off = 32; off; off >>= 1) a = fmaxf(a, __shfl_xor(a, off));
  return a;
}

// ---------------- packed dot helpers ----------------
__device__ __forceinline__ float dot8p(uint4 w, float4 a, float4 b2){
  float s;
  s  = u2f(w.x<<16)*a.x  + u2f(w.x&0xffff0000u)*a.y;
  s += u2f(w.y<<16)*a.z  + u2f(w.y&0xffff0000u)*a.w;
  s += u2f(w.z<<16)*b2.x + u2f(w.z&0xffff0000u)*b2.y;
  s += u2f(w.w<<16)*b2.z + u2f(w.w&0xffff0000u)*b2.w;
  return s;
}
__device__ __forceinline__ float dot4f(float4 w, float4 x){
  return w.x*x.x + w.y*x.y + w.z*x.z + w.w*x.w;
}
__device__ __forceinline__ uint4 pk8(float4 a, float4 b2){
  uint4 r;
  r.x = (u32)f2bf(a.x)  | ((u32)f2bf(a.y)<<16);
  r.y = (u32)f2bf(a.z)  | ((u32)f2bf(a.w)<<16);
  r.z = (u32)f2bf(b2.x) | ((u32)f2bf(b2.y)<<16);
  r.w = (u32)f2bf(b2.z) | ((u32)f2bf(b2.w)<<16);
  return r;
}

#define SMEM_BYTES 150048

// wave-8 deferred log-softmax jobs (round-robin across blocks, off critical path)
#define RUN_JOBS() do { \
  if (wv == 8){ \
    if (dBV && b == dBo1){ \
      u64 v_ = pollt(XS + dBSlot*64 + lane, dBTag); \
      float x0 = sA0 + bf2f((u16)(v_ & 0xffff)); \
      float x1 = sA1 + bf2f((u16)((v_>>16) & 0xffff)); \
      x0 = (lane < dBcur) ? x0 : -__builtin_inff(); \
      x1 = (lane + 64 < dBcur) ? x1 : -__builtin_inff(); \
      float m_ = wredmaxsh(fmaxf(x0, x1)); \
      float s_ = wredsh(__expf(x0 - m_) + __expf(x1 - m_)); \
      float la_ = (dBarg < 64) ? __shfl(x0, dBarg) : __shfl(x1, dBarg - 64); \
      if (lane == 0) nllw += (m_ + logf(s_)) - la_; \
    } \
    if (dAV && (b == dAo1 || b == dAo2)){ \
      const u64* P_ = XP + ((size_t)(dASlot*64 + lane))*64 + ((b == dAo2) ? 32 : 0); \
      float h0_ = 0.f, h1_ = 0.f; \
      for (int c_ = 0; c_ < 2; ++c_){ \
        u64 vv_[16]; int bad_; int nn_ = 0; \
        do { bad_ = 0; \
          _Pragma("unroll") for (int j_ = 0; j_ < 16; ++j_) vv_[j_] = gld64(P_ + c_*16 + j_); \
          _Pragma("unroll") for (int j_ = 0; j_ < 16; ++j_) bad_ |= ((u32)(vv_[j_]>>32) != dATag); \
        } while (bad_ && ++nn_ < (1<<20)); \
        _Pragma("unroll") for (int j_ = 0; j_ < 16; ++j_){ \
          h0_ += bf2f((u16)(vv_[j_] & 0xffff)); h1_ += bf2f((u16)((vv_[j_]>>16) & 0xffff)); } \
      } \
      if (b == dAo2) gst64(XS + dASlot*64 + lane, ((u64)dATag<<32) | (u32)f2bf(h0_) | ((u32)f2bf(h1_)<<16)); \
      else { sA0 = h0_; sA1 = h1_; } \
    } \
    if (aeV && b == aeOwn){ \
      u64 v_ = pollt(XE + aeSlot*64 + lane, aeTag); \
      float p0_ = wredsh(bf2f((u16)(v_ & 0xffff))); \
      float p1_ = wredsh(bf2f((u16)((v_>>16) & 0xffff))); \
      if (lane == 0){ \
        float l0_ = p0_ + be2_0, l1_ = p1_ + be2_1; \
        float m_ = fmaxf(l0_, l1_); \
        nllw += m_ + logf(__expf(l0_-m_) + __expf(l1_-m_)) - (aeSel ? l1_ : l0_); \
      } \
    } \
  } \
} while(0)

#define SHIFT_JOBS() do { \
  dBV = dAV; dBSlot = dASlot; dBo1 = dAo1; dBTag = dATag; dBcur = dAcur; dBarg = dAarg; \
  dAV = 0; aeV = 0; \
} while(0)

__global__ void __launch_bounds__(NTHR, 1)
dgmg_kernel(const int* __restrict__ actions, const int* __restrict__ argseq,
            const float* __restrict__ node_init, const float* __restrict__ w_nip, const float* __restrict__ b_nip,
            const float* __restrict__ w_e1, const float* __restrict__ b_e1,
            const float* __restrict__ w_e2, const float* __restrict__ b_e2,
            const float* __restrict__ w_q, const float* __restrict__ b_q,
            const float* __restrict__ w_k,
            const float* __restrict__ wih_n, const float* __restrict__ whh_n,
            const float* __restrict__ bih_n, const float* __restrict__ bhh_n,
            const float* __restrict__ wih_g, const float* __restrict__ whh_g,
            const float* __restrict__ bih_g, const float* __restrict__ bhh_g,
            const float* __restrict__ graph0,
            float* __restrict__ out, unsigned char* __restrict__ ws)
{
  extern __shared__ unsigned char smem[];
  u16* s_wihg = (u16*)smem;                 // [24][512] packed bf16
  u16* s_whhg = s_wihg + 24*512;
  u16* s_wihn = s_whhg + 24*512;
  u16* s_whhn = s_wihn + 24*512;
  u16* s_we1  = s_whhn + 24*512;            // [8][1024]
  u16* s_wq   = s_we1 + 8*1024;             // [8][1024]
  float* s_g    = (float*)(s_wq + 8*1024);  // staged graph vector
  float* s_nc   = s_g + 512;                // staged ncur (current node, post-GRU_n)
  float* s_curv = s_nc + 512;               // current node vector pre-update
  float* s_h0   = s_curv + 512;             // fresh-node embedding
  float* s_kloc = s_h0 + 512;               // [8][128] transposed k-cache: [dim][node]
  float* s_bihg = s_kloc + 1024;            // [24]
  float* s_bhhg = s_bihg + 24;
  float* s_bihn = s_bhhg + 24;
  float* s_bhhn = s_bihn + 24;
  float* s_be1  = s_bhhn + 24;              // [8]
  float* s_bq   = s_be1 + 8;                // [8]
  float* s_q8   = s_bq + 8;                 // [8]
  float* s_red  = s_q8 + 8;                 // [16]
  u16*   s_gin  = (u16*)(s_red + 16);       // [128][24] gi_n freeze cache (bf16, bias incl.)

  const int b = blockIdx.x, tid = threadIdx.x;
  const int wv = tid >> 6, lane = tid & 63;
  const int d = b*8 + ((wv < 8) ? wv : 0);

  // workspace: tagged u64 atoms
  u64* Xng = (u64*)ws;         // [2][512][2]: per dim {ncur, g} adjacent (same cache line)
  u64* Xh  = Xng + 2048;       // [512] h0 broadcast
  u64* XE  = Xh + 512;         // [4][64] edge-logit partials (2xbf16)
  u64* XP  = XE + 256;         // [4][64][64] dest-logit partials
  u64* XS  = XP + 16384;       // [4][64] dest half-sums
  u64* XN  = XS + 256;         // [64] final nll pieces

  // ---------------- init: biases + packed bf16 weight slices ----------------
  if (tid < 24){
    int ld = tid/3, gt = tid%3;
    int row = gt*512 + b*8 + ld;
    s_bihg[tid] = bih_g[row]; s_bhhg[tid] = bhh_g[row];
    s_bihn[tid] = bih_n[row]; s_bhhn[tid] = bhh_n[row];
  }
  if (tid < 8){ s_be1[tid] = b_e1[b*8+tid]; s_bq[tid] = b_q[b*8+tid]; }

  for (int r = wv; r < 24; r += 9){           // all 9 waves pack
    int ld = r/3, gt = r%3;
    long grow = (long)(gt*512 + b*8 + ld) * 512;
    float4 a0, a1;
    a0 = *(const float4*)&wih_g[grow + lane*8]; a1 = *(const float4*)&wih_g[grow + lane*8 + 4];
    *(uint4*)&s_wihg[r*512 + lane*8] = pk8(a0, a1);
    a0 = *(const float4*)&whh_g[grow + lane*8]; a1 = *(const float4*)&whh_g[grow + lane*8 + 4];
    *(uint4*)&s_whhg[r*512 + lane*8] = pk8(a0, a1);
    a0 = *(const float4*)&wih_n[grow + lane*8]; a1 = *(const float4*)&wih_n[grow + lane*8 + 4];
    *(uint4*)&s_wihn[r*512 + lane*8] = pk8(a0, a1);
    a0 = *(const float4*)&whh_n[grow + lane*8]; a1 = *(const float4*)&whh_n[grow + lane*8 + 4];
    *(uint4*)&s_whhn[r*512 + lane*8] = pk8(a0, a1);
  }
  if (wv < 8){
    long grow = (long)(b*8 + wv) * 1024;
    #pragma unroll
    for (int h = 0; h < 2; ++h){
      float4 a0 = *(const float4*)&w_e1[grow + h*512 + lane*8];
      float4 a1 = *(const float4*)&w_e1[grow + h*512 + lane*8 + 4];
      *(uint4*)&s_we1[wv*1024 + h*512 + lane*8] = pk8(a0, a1);
      float4 q0 = *(const float4*)&w_q[grow + h*512 + lane*8];
      float4 q1 = *(const float4*)&w_q[grow + h*512 + lane*8 + 4];
      *(uint4*)&s_wq[wv*1024 + h*512 + lane*8] = pk8(q0, q1);
    }
  }
  float we2_0 = w_e2[d], we2_1 = w_e2[512+d];
  float be2_0 = b_e2[0], be2_1 = b_e2[1];
  float nllw = 0.f, sA0 = 0.f, sA1 = 0.f;

  // job state
  int aeV=0, aeSlot=0, aeSel=0, aeOwn=0; u32 aeTag=0;
  int dAV=0, dASlot=0, dAo1=0, dAo2=0, dAcur=0, dAarg=0; u32 dATag=0;
  int dBV=0, dBSlot=0, dBo1=0, dBcur=0, dBarg=0; u32 dBTag=0;
  int ecnt=0, dcnt=0;

  // ---------------- INIT (tag 1): broadcast h0 ----------------
  if (tid < 512) s_g[tid] = node_init[tid];
  __syncthreads();
  // register-cache per-wave bias constants
  float cbg_r=0,cbg_z=0,bg_ni=0,bg_nh=0, bh_gr=0,bh_gz=0;
  float bn_r=0,bn_z=0,bn_nh=0, fb_r=0,fb_z=0,fb_n=0, be1w=0,bqw=0;
  if (wv < 8){
    cbg_r = s_bihg[wv*3+0]+s_bhhg[wv*3+0];
    cbg_z = s_bihg[wv*3+1]+s_bhhg[wv*3+1];
    bg_ni = s_bihg[wv*3+2]; bg_nh = s_bhhg[wv*3+2];
    bh_gr = s_bhhg[wv*3+0]; bh_gz = s_bhhg[wv*3+1];
    bn_r = s_bhhn[wv*3+0]; bn_z = s_bhhn[wv*3+1]; bn_nh = s_bhhn[wv*3+2];
    fb_r = s_bihn[wv*3+0]; fb_z = s_bihn[wv*3+1]; fb_n = s_bihn[wv*3+2];
    be1w = s_be1[wv]; bqw = s_bq[wv];
    const float* wr = w_nip + (long)d*512;
    float4 wa = *(const float4*)&wr[lane*8], wb2 = *(const float4*)&wr[lane*8+4];
    float4 xa = *(float4*)&s_g[lane*8], xb = *(float4*)&s_g[lane*8+4];
    float h0d = wred(dot4f(wa,xa)+dot4f(wb2,xb)) + b_nip[d];
    if (lane == 0) gst64(&Xh[d], (1ull<<32) | f2u(h0d));
  }
  u32 ph = 2;

  float gi0r=0,gi0z=0,gi0n=0, ghn0r=0,ghn0z=0,ghn0n=0;  // caches of *@h0
  int cur = -1, have_se = 0;
  bool first_an = true;

  // ---------------- main sequential scan ----------------
  for (int t = 0; t < LSEQ; ++t){
    int a = actions[t];
    if (a == 1) continue;                    // ADD_EDGE fused into its CD phase
    if (a == 3){ have_se = 1; continue; }    // STOP_EDGE fused into next AN / drain
    if (a < 0 || a >= 4) continue;

    int t1 = (t+1 < LSEQ) ? actions[t+1] : -1;
    int nxt = (t1 == 1);
    int i2 = (t+2 < LSEQ) ? t+2 : LSEQ-1;
    int chn = nxt ? argseq[i2] : 0;          // lookahead: next edge's destination

    if (a == 0){ // ======== ADD_NODE (1 phase; absorbs pending STOP_EDGE) ========
      int eslot = ecnt & 3;
      if (first_an){
        if (tid < 512){ u64 v = pollt(&Xh[tid], 1u); s_h0[tid] = u2f((u32)v); s_g[tid] = graph0[tid]; }
      } else {
        u32 gtag = ph-1; int gpar = gtag & 1;
        if (tid < 512){ u64 v = pollt(&Xng[(gpar*512+tid)*2+1], gtag); s_g[tid] = u2f((u32)v); }
      }
      __syncthreads();
      RUN_JOBS();
      if (wv < 8){
        float4 xg_a = *(float4*)&s_g[lane*8], xg_b = *(float4*)&s_g[lane*8+4];
        float4 xc_a = *(float4*)&s_curv[lane*8], xc_b = *(float4*)&s_curv[lane*8+4];
        const u32* Whg = (const u32*)s_whhg;
        if (first_an){
          float4 xh_a = *(float4*)&s_h0[lane*8], xh_b = *(float4*)&s_h0[lane*8+4];
          const u32* Wig = (const u32*)s_wihg; const u32* Wn = (const u32*)s_whhn;
          gi0r = wred(dot8p(*(const uint4*)&Wig[(wv*3+0)*256+lane*4], xh_a,xh_b)) + s_bihg[wv*3+0];
          gi0z = wred(dot8p(*(const uint4*)&Wig[(wv*3+1)*256+lane*4], xh_a,xh_b)) + s_bihg[wv*3+1];
          gi0n = wred(dot8p(*(const uint4*)&Wig[(wv*3+2)*256+lane*4], xh_a,xh_b)) + s_bihg[wv*3+2];
          ghn0r = wred(dot8p(*(const uint4*)&Wn[(wv*3+0)*256+lane*4], xh_a,xh_b)) + bn_r;
          ghn0z = wred(dot8p(*(const uint4*)&Wn[(wv*3+1)*256+lane*4], xh_a,xh_b)) + bn_z;
          ghn0n = wred(dot8p(*(const uint4*)&Wn[(wv*3+2)*256+lane*4], xh_a,xh_b)) + bn_nh;
        }
        { // g' = GRU_g(h0, g): FIRST — the serial cross-block chain
          float ghr = wred(dot8p(*(const uint4*)&Whg[(wv*3+0)*256+lane*4], xg_a,xg_b)) + bh_gr;
          float ghz = wred(dot8p(*(const uint4*)&Whg[(wv*3+1)*256+lane*4], xg_a,xg_b)) + bh_gz;
          float ghn = wred(dot8p(*(const uint4*)&Whg[(wv*3+2)*256+lane*4], xg_a,xg_b)) + bg_nh;
          float r_ = sigm(gi0r + ghr), z_ = sigm(gi0z + ghz);
          float n_ = tanhf(gi0n + r_*ghn);
          if (lane == 0) gst64(&Xng[((ph&1)*512+d)*2+1], ((u64)ph<<32) | f2u((1.f-z_)*n_ + z_*s_g[d]));  // FIRE
        }
        float fr=0.f, fz=0.f, fn=0.f;
        if (cur >= 0){ // freeze prev node BEFORE lookahead read (block-local caches)
          const u32* Win = (const u32*)s_wihn;
          fr = wred(dot8p(*(const uint4*)&Win[(wv*3+0)*256+lane*4], xc_a,xc_b)) + fb_r;
          fz = wred(dot8p(*(const uint4*)&Win[(wv*3+1)*256+lane*4], xc_a,xc_b)) + fb_z;
          fn = wred(dot8p(*(const uint4*)&Win[(wv*3+2)*256+lane*4], xc_a,xc_b)) + fb_n;
          float kv;
          {
            const float* wkr = w_k + (long)d*512;
            float4 ka = *(const float4*)&wkr[lane*8], kb2 = *(const float4*)&wkr[lane*8+4];
            kv = wred(dot4f(ka,xc_a)+dot4f(kb2,xc_b));
          }
          if (lane == 0){
            s_gin[cur*24+wv*3+0] = f2bf(fr); s_gin[cur*24+wv*3+1] = f2bf(fz); s_gin[cur*24+wv*3+2] = f2bf(fn);
            s_kloc[wv*128 + cur] = kv;
          }
        }
        if (nxt){ // ncur1 = GRU_n(chosen1, h0); forward freeze regs if chn==cur
          float gr = (chn == cur && cur >= 0) ? fr : bf2f(s_gin[chn*24+wv*3+0]);
          float gz = (chn == cur && cur >= 0) ? fz : bf2f(s_gin[chn*24+wv*3+1]);
          float gn = (chn == cur && cur >= 0) ? fn : bf2f(s_gin[chn*24+wv*3+2]);
          float r2 = sigm(gr + ghn0r), z2 = sigm(gz + ghn0z);
          float n2 = tanhf(gn + r2*ghn0n);
          if (lane == 0) gst64(&Xng[((ph&1)*512+d)*2], ((u64)ph<<32) | f2u((1.f-z2)*n2 + z2*s_h0[d]));
        }
        if (have_se){ // deferred STOP_EDGE partials
          const u32* Re = (const u32*)s_we1 + wv*512;
          float pe = dot8p(*(const uint4*)&Re[lane*4], xg_a,xg_b) + dot8p(*(const uint4*)&Re[256+lane*4], xc_a,xc_b);
          float hv = fmaxf(wred(pe) + be1w, 0.f);
          if (lane == 0){ s_red[wv*2+0] = hv*we2_0; s_red[wv*2+1] = hv*we2_1; }
        }
      }
      __syncthreads();
      if (have_se && tid == 0){
        float p0 = 0.f, p1 = 0.f;
        #pragma unroll
        for (int i = 0; i < 8; ++i){ p0 += s_red[i*2]; p1 += s_red[i*2+1]; }
        gst64(&XE[eslot*64 + b], ((u64)ph<<32) | (u32)f2bf(p0) | ((u32)f2bf(p1)<<16));
      }
      if (tid < 512) s_curv[tid] = s_h0[tid];
      SHIFT_JOBS();
      if (have_se){ aeV=1; aeSlot=eslot; aeSel=1; aeOwn=ecnt&63; aeTag=ph; ecnt++; }
      have_se = 0; first_an = false;
      cur += 1; ph += 1;
    }
    else { // ======== CHOOSE_DEST: ONE phase (AE fused; ncur pipelined ahead) ========
      int arg = argseq[t];
      int eslot = ecnt & 3, dslot = dcnt & 1;
      {
        u32 gtag = ph-1; int gpar = gtag & 1;
        if (tid < 512){
          u64 v0, v1; int n = 0;
          const u64* p = &Xng[(gpar*512 + tid)*2];
          do { v0 = gld64(p); v1 = gld64(p+1); }
          while ((((u32)(v0>>32) != gtag) || ((u32)(v1>>32) != gtag)) && ++n < (1<<20));
          s_nc[tid] = u2f((u32)v0); s_g[tid] = u2f((u32)v1);
        }
      }
      __syncthreads();
      RUN_JOBS();
      if (wv < 8){
        float4 xn_a = *(float4*)&s_nc[lane*8], xn_b = *(float4*)&s_nc[lane*8+4];
        float4 xg_a = *(float4*)&s_g[lane*8],  xg_b = *(float4*)&s_g[lane*8+4];
        float4 xc_a = *(float4*)&s_curv[lane*8], xc_b = *(float4*)&s_curv[lane*8+4];
        const u32* Wn = (const u32*)s_whhn; const u32* Wig = (const u32*)s_wihg; const u32* Whg = (const u32*)s_whhg;
        { // 1) fire g_j FIRST (critical cross-block chain); r/z partials pre-combined
          float pr = dot8p(*(const uint4*)&Wig[(wv*3+0)*256+lane*4], xn_a,xn_b)
                   + dot8p(*(const uint4*)&Whg[(wv*3+0)*256+lane*4], xg_a,xg_b);
          float pz = dot8p(*(const uint4*)&Wig[(wv*3+1)*256+lane*4], xn_a,xn_b)
                   + dot8p(*(const uint4*)&Whg[(wv*3+1)*256+lane*4], xg_a,xg_b);
          float r_ = sigm(wred(pr) + cbg_r);
          float z_ = sigm(wred(pz) + cbg_z);
          float gin_ = wred(dot8p(*(const uint4*)&Wig[(wv*3+2)*256+lane*4], xn_a,xn_b)) + bg_ni;
          float ghn_ = wred(dot8p(*(const uint4*)&Whg[(wv*3+2)*256+lane*4], xg_a,xg_b)) + bg_nh;
          float n_ = tanhf(gin_ + r_*ghn_);
          if (lane == 0) gst64(&Xng[((ph&1)*512+d)*2+1], ((u64)ph<<32) | f2u((1.f-z_)*n_ + z_*s_g[d])); // FIRE g2
        }
        if (nxt){ // 2) fire ncur_{j+1} = GRU_n(chosen_{j+1}, ncur_j)
          float ghr = wred(dot8p(*(const uint4*)&Wn[(wv*3+0)*256+lane*4], xn_a,xn_b)) + bn_r;
          float ghz = wred(dot8p(*(const uint4*)&Wn[(wv*3+1)*256+lane*4], xn_a,xn_b)) + bn_z;
          float ghn = wred(dot8p(*(const uint4*)&Wn[(wv*3+2)*256+lane*4], xn_a,xn_b)) + bn_nh;
          float gr = bf2f(s_gin[chn*24+wv*3+0]), gz = bf2f(s_gin[chn*24+wv*3+1]), gn = bf2f(s_gin[chn*24+wv*3+2]);
          float r_ = sigm(gr+ghr), z_ = sigm(gz+ghz);
          float n_ = tanhf(gn + r_*ghn);
          if (lane == 0) gst64(&Xng[((ph&1)*512+d)*2], ((u64)ph<<32) | f2u((1.f-z_)*n_ + z_*s_nc[d])); // FIRE ncur
        }
        { // 3) q_j and AE e-logit partials from (g_{j-1}, curv_{j-1})
          const u32* Rq = (const u32*)s_wq + wv*512;
          float pq = dot8p(*(const uint4*)&Rq[lane*4], xg_a,xg_b) + dot8p(*(const uint4*)&Rq[256+lane*4], xc_a,xc_b);
          float qd = wred(pq) + bqw;
          const u32* Re = (const u32*)s_we1 + wv*512;
          float pe = dot8p(*(const uint4*)&Re[lane*4], xg_a,xg_b) + dot8p(*(const uint4*)&Re[256+lane*4], xc_a,xc_b);
          float hv = fmaxf(wred(pe) + be1w, 0.f);
          if (lane == 0){ s_q8[wv] = qd; s_red[wv*2+0] = hv*we2_0; s_red[wv*2+1] = hv*we2_1; }
        }
      }
      __syncthreads();
      if (tid < 64){ // dest-logit partials: local k slices x local q dims
        float pl0 = 0.f, pl1 = 0.f;
        #pragma unroll
        for (int k = 0; k < 8; ++k){
          pl0 += s_kloc[k*128 + tid]      * s_q8[k];
          pl1 += s_kloc[k*128 + tid + 64] * s_q8[k];
        }
        gst64(&XP[((size_t)(dslot*64 + tid))*64 + b],
              ((u64)ph<<32) | (u32)f2bf(pl0) | ((u32)f2bf(pl1)<<16));
      }
      if (tid == 64){
        float p0 = 0.f, p1 = 0.f;
        #pragma unroll
        for (int i = 0; i < 8; ++i){ p0 += s_red[i*2]; p1 += s_red[i*2+1]; }
        gst64(&XE[eslot*64 + b], ((u64)ph<<32) | (u32)f2bf(p0) | ((u32)f2bf(p1)<<16));
      }
      if (tid < 512) s_curv[tid] = s_nc[tid];
      SHIFT_JOBS();
      aeV=1; aeSlot=eslot; aeSel=0; aeOwn=ecnt&63; aeTag=ph; ecnt++;
      dAV=1; dASlot=dslot; dAo1=(2*dcnt)&63; dAo2=(2*dcnt+1)&63; dAcur=cur; dAarg=arg; dATag=ph;
      dcnt++;
      ph += 1;
    }
  }

  // ---------------- drain: V1 (final SE partials + last stage-B), V2 (collect) ----------------
  {
    int eslot = ecnt & 3;
    u32 gtag = ph-1; int gpar = gtag & 1;
    if (tid < 512){ u64 v = pollt(&Xng[(gpar*512+tid)*2+1], gtag); s_g[tid] = u2f((u32)v); }
    __syncthreads();
    RUN_JOBS();                               // jobs due this phase
    if (have_se && wv < 8){
      float4 xg_a = *(float4*)&s_g[lane*8], xg_b = *(float4*)&s_g[lane*8+4];
      float4 xc_a = *(float4*)&s_curv[lane*8], xc_b = *(float4*)&s_curv[lane*8+4];
      const u32* Re = (const u32*)s_we1 + wv*512;
      float pe = dot8p(*(const uint4*)&Re[lane*4], xg_a,xg_b) + dot8p(*(const uint4*)&Re[256+lane*4], xc_a,xc_b);
      float hv = fmaxf(wred(pe) + be1w, 0.f);
      if (lane == 0){ s_red[wv*2] = hv*we2_0; s_red[wv*2+1] = hv*we2_1; }
    }
    __syncthreads();
    if (have_se && tid == 0){
      float p0 = 0.f, p1 = 0.f;
      #pragma unroll
      for (int i = 0; i < 8; ++i){ p0 += s_red[i*2]; p1 += s_red[i*2+1]; }
      gst64(&XE[eslot*64 + b], ((u64)ph<<32) | (u32)f2bf(p0) | ((u32)f2bf(p1)<<16));
    }
    SHIFT_JOBS();
    RUN_JOBS();                               // stage-B of the last CHOOSE_DEST
    if (wv == 8){
      if (have_se && b == 0){
        u64 v = pollt(&XE[eslot*64 + lane], ph);
        float p0 = wredsh(bf2f((u16)(v & 0xffff)));
        float p1 = wredsh(bf2f((u16)((v>>16) & 0xffff)));
        if (lane == 0){
          float l0 = p0 + be2_0, l1 = p1 + be2_1;
          float m = fmaxf(l0, l1);
          nllw += m + logf(__expf(l0-m) + __expf(l1-m)) - l1;   // STOP_EDGE selects idx 1
        }
      }
      if (lane == 0) gst64(&XN[b], (0xFFFFull<<32) | f2u(nllw));
      if (b == 0){
        u64 v = pollt(&XN[lane], 0xFFFFu);
        float tot = wredsh(u2f((u32)v));
        if (lane == 0) out[0] = tot;
      }
    }
  }
}

extern "C" void kernel_launch(void* const* d_in, const int* in_sizes, int n_in,
                              void* d_out, int out_size, void* d_ws, size_t ws_size,
                              hipStream_t stream) {
  (void)in_sizes; (void)n_in; (void)out_size; (void)ws_size;
  // zero all tag-atom regions (19520 u64) — exact-match tags then poison/replay-safe
  hipMemsetAsync(d_ws, 0, 156160, stream);
  hipFuncSetAttribute((const void*)dgmg_kernel,
                      hipFuncAttributeMaxDynamicSharedMemorySize, SMEM_BYTES);
  dgmg_kernel<<<NBLK, NTHR, SMEM_BYTES, stream>>>(
      (const int*)d_in[0], (const int*)d_in[1],
      (const float*)d_in[2], (const float*)d_in[3], (const float*)d_in[4],
      (const float*)d_in[5], (const float*)d_in[6],
      (const float*)d_in[7], (const float*)d_in[8],
      (const float*)d_in[9], (const float*)d_in[10],
      (const float*)d_in[11],                      /* w_k ; b_k unused (cancels) */
      (const float*)d_in[13], (const float*)d_in[14],
      (const float*)d_in[15], (const float*)d_in[16],
      (const float*)d_in[17], (const float*)d_in[18],
      (const float*)d_in[19], (const float*)d_in[20],
      (const float*)d_in[21],
      (float*)d_out, (unsigned char*)d_ws);
}